// Round 6
// baseline (216.867 us; speedup 1.0000x reference)
//
#include <hip/hip_runtime.h>

typedef float f32x4 __attribute__((ext_vector_type(4)));
typedef _Float16 h8 __attribute__((ext_vector_type(8)));
typedef unsigned short us8 __attribute__((ext_vector_type(8)));
typedef unsigned short us4 __attribute__((ext_vector_type(4)));

#define DEV __device__ __forceinline__
#define BARRIER()  asm volatile("s_barrier" ::: "memory")
#define LGKM0()    asm volatile("s_waitcnt lgkmcnt(0)" ::: "memory")
#define VMCNT6()   asm volatile("s_waitcnt vmcnt(6)" ::: "memory")

constexpr int Bb = 32, Nn = 1024, Mm = 576, Dd = 768;
constexpr float L2E = 1.44269504088896340736f;

// ws layout (ushort elems), fragment-major for 16x16x32 f16 MFMA:
//   Kf: [b][kvtile 36][dc 24][lane 64][8]   B-frag: K[kvt*16+(l&15)][dc*32+(l>>4)*8+j]
//   Vf: [b][kc 18][dtile 48][lane 64][8]    B-frag: V[kc*32+(l>>4)*8+j][dt*16+(l&15)]
constexpr size_t KF_ELEMS = (size_t)Bb * 36 * 24 * 512;  // 14,155,776

DEV unsigned short f2h(float x) {
  _Float16 h = (_Float16)x;
  return __builtin_bit_cast(unsigned short, h);
}
DEV void gll16(const void* g, void* l) {
  __builtin_amdgcn_global_load_lds(
      (const __attribute__((address_space(1))) void*)g,
      (__attribute__((address_space(3))) void*)l, 16, 0, 0);
}

// ---------------- pre-pass: K -> Kf, Vf (fragment-major f16)
__global__ __launch_bounds__(256)
void fusion_prep(const float* __restrict__ K, unsigned short* __restrict__ Kf,
                 unsigned short* __restrict__ Vf)
{
  const int t = threadIdx.x;
  const int b = blockIdx.x / 24, dc = blockIdx.x % 24;
  const int l = t & 63;
  // --- Kf ---
  {
    const int lt = t >> 6;
    const int ro = l & 15, go = l >> 4;
#pragma unroll
    for (int it = 0; it < 9; ++it) {
      const int kvt = it * 4 + lt;
      const float* src = K + ((size_t)(b * Mm + kvt * 16 + ro)) * Dd + dc * 32 + go * 8;
      f32x4 v0 = *(const f32x4*)src;
      f32x4 v1 = *(const f32x4*)(src + 4);
      us8 h;
      h[0]=f2h(v0[0]); h[1]=f2h(v0[1]); h[2]=f2h(v0[2]); h[3]=f2h(v0[3]);
      h[4]=f2h(v1[0]); h[5]=f2h(v1[1]); h[6]=f2h(v1[2]); h[7]=f2h(v1[3]);
      *(us8*)&Kf[(((size_t)((b * 36 + kvt) * 24 + dc)) << 9) + l * 8] = h;
    }
  }
  // --- Vf ---
  {
    const int kch = t >> 7;
    const int dtl = (t >> 6) & 1;
    const int d = dc * 32 + dtl * 16 + (l & 15);
    const int kvo = (l >> 4) * 8;
#pragma unroll
    for (int it = 0; it < 9; ++it) {
      const int kc = it * 2 + kch;
      const int kv0 = kc * 32 + kvo;
      us8 o;
#pragma unroll
      for (int j = 0; j < 8; ++j)
        o[j] = f2h(K[((size_t)(b * Mm + kv0 + j)) * Dd + d]);
      *(us8*)&Vf[(((size_t)((b * 18 + kc) * 48 + dc * 2 + dtl)) << 9) + l * 8] = o;
    }
  }
}

// ---------------- main: counted-vmcnt 3-buffer pipelined QK, 1 raw barrier/chunk
// LDS map (bytes): bufK[3] @ {0, 36864, 73728} (36 KB each)
//                  qbuf[2] @ 110592 + {0, 16384}  ([qt8][hl2][lane64][16B])
//                  sP (128x576 f16, pitch 1152 B, 16B-unit XOR swizzle) aliases @ 0..147456
__global__ __launch_bounds__(1024)
void fusion_main(const float* __restrict__ Q, const unsigned short* __restrict__ Kf,
                 const unsigned short* __restrict__ Vf, float* __restrict__ Out)
{
  __shared__ alignas(16) unsigned char lds[147456];
  __shared__ float sRa[4][128];
  __shared__ float sRb[4][128];

  const int tid  = threadIdx.x;
  const int lane = tid & 63;
  const int w    = tid >> 6;      // 0..15
  const int g    = lane >> 4;
  const int ln   = lane & 15;
  const int wq   = w >> 2;        // QK: 0..3, q rows [wq*32,+32)
  const int wkv  = w & 3;         // QK: kv slice [wkv*144,+144)
  const int wq2  = w >> 3;        // PV: 0..1, q rows [wq2*64,+64)
  const int wd8  = w & 7;         // PV: d slice [wd8*96,+96)

  // XCD swizzle
  const int bid = blockIdx.x;
  const int xcd = bid & 7, ii = bid >> 3;
  const int b  = (xcd << 2) | (ii >> 3);
  const int q0 = (ii & 7) * 128;

  const float* Qb = Q + ((size_t)(b * Nn + q0)) * Dd;
  const unsigned char* KfB = (const unsigned char*)Kf + ((size_t)(b * 36 * 24) << 10);
  const unsigned short* VfB = Vf + ((size_t)(b * 18 * 48) << 9);

  // Q staging constants
  const int qt_s = w >> 1;        // 0..7
  const int jh_s = w & 1;         // 0..1
  const float* qsrc = Qb + (size_t)(qt_s * 16 + ln) * Dd + g * 8 + jh_s * 4;
  unsigned char* qdst = lds + 110592 + qt_s * 2048 + lane * 16 + jh_s * 8;

  const bool loader = (w < 12);
  const int u0 = w * 3;           // K staging units for loader waves

  // ---------------- prologue: Q(0),Q(1) loads; K(0..2) gll16; write qbuf[0]
  f32x4 qv_cur = *(const f32x4*)qsrc;            // Q chunk 0
  f32x4 qv_nxt = *(const f32x4*)(qsrc + 32);     // Q chunk 1
  if (loader) {
#pragma unroll
    for (int cc = 0; cc < 3; ++cc)
#pragma unroll
      for (int j = 0; j < 3; ++j) {
        const int u = u0 + j;
        gll16(KfB + (((size_t)(u * 24 + cc)) << 10) + (lane << 4),
              lds + cc * 36864 + u * 1024);
      }
  }
  {
    us4 hv, lv;
#pragma unroll
    for (int k = 0; k < 4; ++k) {
      float x = qv_cur[k] * L2E;
      _Float16 hh = (_Float16)x;
      hv[k] = __builtin_bit_cast(unsigned short, hh);
      lv[k] = __builtin_bit_cast(unsigned short, (_Float16)(x - (float)hh));
    }
    *(us4*)qdst = hv;
    *(us4*)(qdst + 1024) = lv;
  }
  if (loader) VMCNT6();   // drain K(0); keep K(1),K(2) in flight
  LGKM0();
  BARRIER();
  __builtin_amdgcn_sched_barrier(0);

  // ---------------- QK main loop: 1 barrier per chunk, counted waits only
  f32x4 acc[2][9];
#pragma unroll
  for (int mt = 0; mt < 2; ++mt)
#pragma unroll
    for (int nt = 0; nt < 9; ++nt) acc[mt][nt] = (f32x4){0.f, 0.f, 0.f, 0.f};

  int cb = 0;  // c % 3
#pragma unroll 1
  for (int c = 0; c < 24; ++c) {
    // step 1: convert + write Q(c+1) (regs loaded at c-1) -> qbuf[(c+1)&1]
    //   compiler's wait for qv_nxt-use = vmcnt(3): drains K(c+1), keeps K(c+2..3)
    if (c < 23) {
      us4 hv, lv;
#pragma unroll
      for (int k = 0; k < 4; ++k) {
        float x = qv_nxt[k] * L2E;
        _Float16 hh = (_Float16)x;
        hv[k] = __builtin_bit_cast(unsigned short, hh);
        lv[k] = __builtin_bit_cast(unsigned short, (_Float16)(x - (float)hh));
      }
      unsigned char* qd = qdst + ((c + 1) & 1) * 16384;
      *(us4*)qd = hv;
      *(us4*)(qd + 1024) = lv;
    }
    // step 2: upfront ds_reads of this chunk's frags (must precede the barrier)
    const unsigned char* qbuf = lds + 110592 + (c & 1) * 16384;
    h8 qh[2], ql[2];
#pragma unroll
    for (int mt = 0; mt < 2; ++mt) {
      qh[mt] = *(const h8*)(qbuf + (wq * 2 + mt) * 2048 + lane * 16);
      ql[mt] = *(const h8*)(qbuf + (wq * 2 + mt) * 2048 + 1024 + lane * 16);
    }
    h8 kfr[9];
#pragma unroll
    for (int nt = 0; nt < 9; ++nt)
      kfr[nt] = *(const h8*)(lds + cb * 36864 + (wkv * 9 + nt) * 1024 + lane * 16);
    // step 3: all reads retired, rendezvous (no vmcnt drain!)
    LGKM0();
    BARRIER();
    __builtin_amdgcn_sched_barrier(0);
    // step 4: issue next loads (Q before K so Q-use wait keeps K prefetch in flight)
    if (c < 22) qv_nxt = *(const f32x4*)(qsrc + (c + 2) * 32);
    if (c < 21 && loader) {
#pragma unroll
      for (int j = 0; j < 3; ++j) {
        const int u = u0 + j;
        gll16(KfB + (((size_t)(u * 24 + c + 3)) << 10) + (lane << 4),
              lds + cb * 36864 + u * 1024);
      }
    }
    // step 5: MFMA cluster (all-hi then all-lo: no dependent back-to-back pairs)
    __builtin_amdgcn_s_setprio(1);
#pragma unroll
    for (int nt = 0; nt < 9; ++nt)
#pragma unroll
      for (int mt = 0; mt < 2; ++mt)
        acc[mt][nt] = __builtin_amdgcn_mfma_f32_16x16x32_f16(qh[mt], kfr[nt], acc[mt][nt], 0, 0, 0);
#pragma unroll
    for (int nt = 0; nt < 9; ++nt)
#pragma unroll
      for (int mt = 0; mt < 2; ++mt)
        acc[mt][nt] = __builtin_amdgcn_mfma_f32_16x16x32_f16(ql[mt], kfr[nt], acc[mt][nt], 0, 0, 0);
    __builtin_amdgcn_s_setprio(0);
    cb = (cb == 2) ? 0 : cb + 1;
  }

  // ---------------- one-shot softmax (exp2 domain)
  float pm[2][4];
#pragma unroll
  for (int mt = 0; mt < 2; ++mt)
#pragma unroll
    for (int i2 = 0; i2 < 4; ++i2) {
      float v = acc[mt][0][i2];
#pragma unroll
      for (int nt = 1; nt < 9; ++nt) v = fmaxf(v, acc[mt][nt][i2]);
      pm[mt][i2] = v;
    }
#pragma unroll
  for (int mk = 1; mk < 16; mk <<= 1)
#pragma unroll
    for (int mt = 0; mt < 2; ++mt)
#pragma unroll
      for (int i2 = 0; i2 < 4; ++i2)
        pm[mt][i2] = fmaxf(pm[mt][i2], __shfl_xor(pm[mt][i2], mk, 64));
  if (ln == 0) {
#pragma unroll
    for (int mt = 0; mt < 2; ++mt)
#pragma unroll
      for (int i2 = 0; i2 < 4; ++i2)
        sRa[wkv][wq * 32 + mt * 16 + g * 4 + i2] = pm[mt][i2];
  }
  __syncthreads();

  float mfin[2][4], ps[2][4];
#pragma unroll
  for (int mt = 0; mt < 2; ++mt)
#pragma unroll
    for (int i2 = 0; i2 < 4; ++i2) {
      const int rw = wq * 32 + mt * 16 + g * 4 + i2;
      mfin[mt][i2] = fmaxf(fmaxf(sRa[0][rw], sRa[1][rw]), fmaxf(sRa[2][rw], sRa[3][rw]));
      ps[mt][i2] = 0.f;
    }
#pragma unroll
  for (int mt = 0; mt < 2; ++mt)
#pragma unroll
    for (int nt = 0; nt < 9; ++nt)
#pragma unroll
      for (int i2 = 0; i2 < 4; ++i2) {
        const float p = exp2f(acc[mt][nt][i2] - mfin[mt][i2]);
        acc[mt][nt][i2] = p;
        ps[mt][i2] += p;
      }
#pragma unroll
  for (int mk = 1; mk < 16; mk <<= 1)
#pragma unroll
    for (int mt = 0; mt < 2; ++mt)
#pragma unroll
      for (int i2 = 0; i2 < 4; ++i2)
        ps[mt][i2] += __shfl_xor(ps[mt][i2], mk, 64);
  if (ln == 0) {
#pragma unroll
    for (int mt = 0; mt < 2; ++mt)
#pragma unroll
      for (int i2 = 0; i2 < 4; ++i2)
        sRb[wkv][wq * 32 + mt * 16 + g * 4 + i2] = ps[mt][i2];
  }
  __syncthreads();

  // normalize P, write to swizzled sP (aliases dead K/Q buffers)
  {
    unsigned short* sPp = (unsigned short*)lds;
#pragma unroll
    for (int mt = 0; mt < 2; ++mt)
#pragma unroll
      for (int i2 = 0; i2 < 4; ++i2) {
        const int rw = wq * 32 + mt * 16 + g * 4 + i2;
        const float inv = 1.0f / ((sRb[0][rw] + sRb[1][rw]) + (sRb[2][rw] + sRb[3][rw]));
#pragma unroll
        for (int nt = 0; nt < 9; ++nt) {
          const int u = wkv * 18 + nt * 2 + (ln >> 3);
          sPp[rw * 576 + ((u ^ (rw & 7)) << 3) + (ln & 7)] = f2h(acc[mt][nt][i2] * inv);
        }
      }
  }
  __syncthreads();

  // ---------------- PV: per wave [64q x 48d] x 2 d-passes; no barriers, TLP hides L2
#pragma unroll 1
  for (int p = 0; p < 2; ++p) {
    f32x4 O[4][3];
#pragma unroll
    for (int mt = 0; mt < 4; ++mt)
#pragma unroll
      for (int nt = 0; nt < 3; ++nt) O[mt][nt] = (f32x4){0.f, 0.f, 0.f, 0.f};

#pragma unroll 1
    for (int kc = 0; kc < 18; ++kc) {
      h8 vf[3];
#pragma unroll
      for (int nt = 0; nt < 3; ++nt)
        vf[nt] = *(const h8*)(VfB + (((size_t)(kc * 48 + wd8 * 6 + p * 3 + nt)) << 9) + lane * 8);
      h8 pa[4];
#pragma unroll
      for (int mt = 0; mt < 4; ++mt) {
        const int row = wq2 * 64 + mt * 16 + ln;
        const int u = kc * 4 + g;
        pa[mt] = *(const h8*)(lds + row * 1152 + ((u ^ (row & 7)) << 4));
      }
#pragma unroll
      for (int nt = 0; nt < 3; ++nt)
#pragma unroll
        for (int mt = 0; mt < 4; ++mt)
          O[mt][nt] = __builtin_amdgcn_mfma_f32_16x16x32_f16(pa[mt], vf[nt], O[mt][nt], 0, 0, 0);
    }

    float* ob = Out + ((size_t)(b * Nn + q0 + wq2 * 64)) * Dd;
#pragma unroll
    for (int mt = 0; mt < 4; ++mt)
#pragma unroll
      for (int nt = 0; nt < 3; ++nt)
#pragma unroll
        for (int i2 = 0; i2 < 4; ++i2)
          ob[(size_t)(mt * 16 + g * 4 + i2) * Dd + wd8 * 96 + p * 48 + nt * 16 + ln] = O[mt][nt][i2];
  }
}

extern "C" void kernel_launch(void* const* d_in, const int* in_sizes, int n_in,
                              void* d_out, int out_size, void* d_ws, size_t ws_size,
                              hipStream_t stream) {
  const float* Q = (const float*)d_in[0];
  const float* K = (const float*)d_in[1];
  float* Out = (float*)d_out;
  unsigned short* Kf = (unsigned short*)d_ws;
  unsigned short* Vf = Kf + KF_ELEMS;
  fusion_prep<<<dim3(Bb * 24), dim3(256), 0, stream>>>(K, Kf, Vf);
  fusion_main<<<dim3(Bb * 8), dim3(1024), 0, stream>>>(Q, Kf, Vf, Out);
}

// Round 7
// 151.488 us; speedup vs baseline: 1.4316x; 1.4316x over previous
//
#include <hip/hip_runtime.h>

typedef float f32x4 __attribute__((ext_vector_type(4)));
typedef _Float16 h8 __attribute__((ext_vector_type(8)));
typedef unsigned short us8 __attribute__((ext_vector_type(8)));

#define DEV __device__ __forceinline__

constexpr int Bb = 32, Nn = 1024, Mm = 576, Dd = 768;
constexpr float L2E = 1.44269504088896340736f;

// ws layout (ushort elems), fragment-major for 16x16x32 f16 MFMA:
//   Kf: [b][kvtile 36][dc 24][lane 64][8]   B-frag: K[kvt*16+(l&15)][dc*32+(l>>4)*8+j]
//   Vf: [b][kc 18][dtile 48][lane 64][8]    B-frag: V[kc*32+(l>>4)*8+j][dt*16+(l&15)]
constexpr size_t KF_ELEMS = (size_t)Bb * 36 * 24 * 512;  // 14,155,776

DEV unsigned short f2h(float x) {
  _Float16 h = (_Float16)x;
  return __builtin_bit_cast(unsigned short, h);
}
DEV void gll16(const void* g, void* l) {
  __builtin_amdgcn_global_load_lds(
      (const __attribute__((address_space(1))) void*)g,
      (__attribute__((address_space(3))) void*)l, 16, 0, 0);
}

// ---------------- pre-pass: K -> Kf, Vf (fragment-major f16)
__global__ __launch_bounds__(256)
void fusion_prep(const float* __restrict__ K, unsigned short* __restrict__ Kf,
                 unsigned short* __restrict__ Vf)
{
  const int t = threadIdx.x;
  const int b = blockIdx.x / 24, dc = blockIdx.x % 24;
  const int l = t & 63;
  // --- Kf ---
  {
    const int lt = t >> 6;
    const int ro = l & 15, go = l >> 4;
#pragma unroll
    for (int it = 0; it < 9; ++it) {
      const int kvt = it * 4 + lt;
      const float* src = K + ((size_t)(b * Mm + kvt * 16 + ro)) * Dd + dc * 32 + go * 8;
      f32x4 v0 = *(const f32x4*)src;
      f32x4 v1 = *(const f32x4*)(src + 4);
      us8 h;
      h[0]=f2h(v0[0]); h[1]=f2h(v0[1]); h[2]=f2h(v0[2]); h[3]=f2h(v0[3]);
      h[4]=f2h(v1[0]); h[5]=f2h(v1[1]); h[6]=f2h(v1[2]); h[7]=f2h(v1[3]);
      *(us8*)&Kf[(((size_t)((b * 36 + kvt) * 24 + dc)) << 9) + l * 8] = h;
    }
  }
  // --- Vf ---
  {
    const int kch = t >> 7;
    const int dtl = (t >> 6) & 1;
    const int d = dc * 32 + dtl * 16 + (l & 15);
    const int kvo = (l >> 4) * 8;
#pragma unroll
    for (int it = 0; it < 9; ++it) {
      const int kc = it * 2 + kch;
      const int kv0 = kc * 32 + kvo;
      us8 o;
#pragma unroll
      for (int j = 0; j < 8; ++j)
        o[j] = f2h(K[((size_t)(b * Mm + kv0 + j)) * Dd + d]);
      *(us8*)&Vf[(((size_t)((b * 18 + kc) * 48 + dc * 2 + dtl)) << 9) + l * 8] = o;
    }
  }
}

// ---------------- main: 64q blocks, 2 blocks/CU; R5-proven __syncthreads pipeline
// LDS (bytes): bufK[2] @ {0, 36864} during QK; sP (64x576 f16, pitch 1152 B,
// 16B-unit XOR swizzle) ALIASES the same 73728 B after QK. Q never touches LDS.
__global__ __launch_bounds__(512, 4)
void fusion_main(const float* __restrict__ Q, const unsigned short* __restrict__ Kf,
                 const unsigned short* __restrict__ Vf, float* __restrict__ Out)
{
  __shared__ alignas(16) unsigned char lds[73728];
  __shared__ float sRa[4][64];
  __shared__ float sRb[4][64];

  const int tid  = threadIdx.x;
  const int lane = tid & 63;
  const int w    = tid >> 6;      // 0..7
  const int g    = lane >> 4;
  const int ln   = lane & 15;
  const int wq   = w >> 2;        // QK: 0..1, q rows [wq*32,+32)
  const int wkv  = w & 3;         // QK: kv slice [wkv*144,+144)

  // XCD swizzle: all 16 q-blocks of a batch on one XCD
  const int bid = blockIdx.x;
  const int xcd = bid & 7, ii = bid >> 3;
  const int b  = (xcd << 2) | (ii >> 4);
  const int q0 = (ii & 15) * 64;

  const float* Qb = Q + ((size_t)(b * Nn + q0)) * Dd;
  const unsigned char* KfB = (const unsigned char*)Kf + ((size_t)(b * 36 * 24) << 10);
  const unsigned short* VfB = Vf + ((size_t)(b * 18 * 48) << 9);

  // per-wave Q row base pointers (col offset g*8; chunk adds c*32)
  const float* qrow0 = Qb + (size_t)(wq * 32 + ln) * Dd + g * 8;
  const float* qrow1 = Qb + (size_t)(wq * 32 + 16 + ln) * Dd + g * 8;

  // ---------------- prologue: K(0) -> buf0; Q(0) -> regs -> cvt
  h8 qhc[2], qlc[2];
  {
#pragma unroll
    for (int nt = w; nt < 36; nt += 8)
      gll16(KfB + ((size_t)(nt * 24) << 10) + (lane << 4), lds + nt * 1024);
    f32x4 a0 = *(const f32x4*)qrow0;
    f32x4 a1 = *(const f32x4*)(qrow0 + 4);
    f32x4 b0 = *(const f32x4*)qrow1;
    f32x4 b1 = *(const f32x4*)(qrow1 + 4);
#pragma unroll
    for (int k = 0; k < 4; ++k) {
      float x0 = a0[k] * L2E; _Float16 h0 = (_Float16)x0;
      float x1 = a1[k] * L2E; _Float16 h1 = (_Float16)x1;
      float y0 = b0[k] * L2E; _Float16 j0 = (_Float16)y0;
      float y1 = b1[k] * L2E; _Float16 j1 = (_Float16)y1;
      qhc[0][k] = h0;     qlc[0][k] = (_Float16)(x0 - (float)h0);
      qhc[0][k+4] = h1;   qlc[0][k+4] = (_Float16)(x1 - (float)h1);
      qhc[1][k] = j0;     qlc[1][k] = (_Float16)(y0 - (float)j0);
      qhc[1][k+4] = j1;   qlc[1][k+4] = (_Float16)(y1 - (float)j1);
    }
    __syncthreads();
  }

  // ---------------- QK: acc[mt 2][nt 9] = [32 q][144 kv]; 2-buffer LDS pipeline
  f32x4 acc[2][9];
#pragma unroll
  for (int mt = 0; mt < 2; ++mt)
#pragma unroll
    for (int nt = 0; nt < 9; ++nt) acc[mt][nt] = (f32x4){0.f, 0.f, 0.f, 0.f};

#pragma unroll 1
  for (int c = 0; c < 24; ++c) {
    const int cur = c & 1, nxt = cur ^ 1;
    const bool stg = (c < 23);
    f32x4 a0, a1, b0, b1;
    if (stg) {  // issue next-chunk K gll16 + Q reg loads early (land under MFMA)
#pragma unroll
      for (int nt = w; nt < 36; nt += 8)
        gll16(KfB + ((size_t)(nt * 24 + c + 1) << 10) + (lane << 4),
              lds + nxt * 36864 + nt * 1024);
      const float* q0p = qrow0 + (c + 1) * 32;
      const float* q1p = qrow1 + (c + 1) * 32;
      a0 = *(const f32x4*)q0p; a1 = *(const f32x4*)(q0p + 4);
      b0 = *(const f32x4*)q1p; b1 = *(const f32x4*)(q1p + 4);
    }
    // compute on cur
    const unsigned char* kb = lds + cur * 36864;
#pragma unroll
    for (int nt = 0; nt < 9; ++nt) {
      const h8 kf = *(const h8*)(kb + (wkv * 9 + nt) * 1024 + lane * 16);
#pragma unroll
      for (int mt = 0; mt < 2; ++mt) {
        acc[mt][nt] = __builtin_amdgcn_mfma_f32_16x16x32_f16(qhc[mt], kf, acc[mt][nt], 0, 0, 0);
        acc[mt][nt] = __builtin_amdgcn_mfma_f32_16x16x32_f16(qlc[mt], kf, acc[mt][nt], 0, 0, 0);
      }
    }
    if (stg) {  // convert next-chunk Q late (loads landed under MFMA)
#pragma unroll
      for (int k = 0; k < 4; ++k) {
        float x0 = a0[k] * L2E; _Float16 h0 = (_Float16)x0;
        float x1 = a1[k] * L2E; _Float16 h1 = (_Float16)x1;
        float y0 = b0[k] * L2E; _Float16 j0 = (_Float16)y0;
        float y1 = b1[k] * L2E; _Float16 j1 = (_Float16)y1;
        qhc[0][k] = h0;     qlc[0][k] = (_Float16)(x0 - (float)h0);
        qhc[0][k+4] = h1;   qlc[0][k+4] = (_Float16)(x1 - (float)h1);
        qhc[1][k] = j0;     qlc[1][k] = (_Float16)(y0 - (float)j0);
        qhc[1][k+4] = j1;   qlc[1][k+4] = (_Float16)(y1 - (float)j1);
      }
    }
    __syncthreads();
  }

  // ---------------- one-shot softmax (exp2 domain; Q pre-scaled by log2 e)
  float pm[2][4];
#pragma unroll
  for (int mt = 0; mt < 2; ++mt)
#pragma unroll
    for (int i2 = 0; i2 < 4; ++i2) {
      float v = acc[mt][0][i2];
#pragma unroll
      for (int nt = 1; nt < 9; ++nt) v = fmaxf(v, acc[mt][nt][i2]);
      pm[mt][i2] = v;
    }
#pragma unroll
  for (int mk = 1; mk < 16; mk <<= 1)
#pragma unroll
    for (int mt = 0; mt < 2; ++mt)
#pragma unroll
      for (int i2 = 0; i2 < 4; ++i2)
        pm[mt][i2] = fmaxf(pm[mt][i2], __shfl_xor(pm[mt][i2], mk, 64));
  if (ln == 0) {
#pragma unroll
    for (int mt = 0; mt < 2; ++mt)
#pragma unroll
      for (int i2 = 0; i2 < 4; ++i2)
        sRa[wkv][wq * 32 + mt * 16 + g * 4 + i2] = pm[mt][i2];
  }
  __syncthreads();

  float mfin[2][4], ps[2][4];
#pragma unroll
  for (int mt = 0; mt < 2; ++mt)
#pragma unroll
    for (int i2 = 0; i2 < 4; ++i2) {
      const int rw = wq * 32 + mt * 16 + g * 4 + i2;
      mfin[mt][i2] = fmaxf(fmaxf(sRa[0][rw], sRa[1][rw]), fmaxf(sRa[2][rw], sRa[3][rw]));
      ps[mt][i2] = 0.f;
    }
#pragma unroll
  for (int mt = 0; mt < 2; ++mt)
#pragma unroll
    for (int nt = 0; nt < 9; ++nt)
#pragma unroll
      for (int i2 = 0; i2 < 4; ++i2) {
        const float p = exp2f(acc[mt][nt][i2] - mfin[mt][i2]);
        acc[mt][nt][i2] = p;
        ps[mt][i2] += p;
      }
#pragma unroll
  for (int mk = 1; mk < 16; mk <<= 1)
#pragma unroll
    for (int mt = 0; mt < 2; ++mt)
#pragma unroll
      for (int i2 = 0; i2 < 4; ++i2)
        ps[mt][i2] += __shfl_xor(ps[mt][i2], mk, 64);
  if (ln == 0) {
#pragma unroll
    for (int mt = 0; mt < 2; ++mt)
#pragma unroll
      for (int i2 = 0; i2 < 4; ++i2)
        sRb[wkv][wq * 32 + mt * 16 + g * 4 + i2] = ps[mt][i2];
  }
  __syncthreads();   // also: all QK reads of bufK done -> safe to alias sP

  // normalize P, write to swizzled sP (aliases dead bufK)
  {
    unsigned short* sPp = (unsigned short*)lds;
#pragma unroll
    for (int mt = 0; mt < 2; ++mt)
#pragma unroll
      for (int i2 = 0; i2 < 4; ++i2) {
        const int rw = wq * 32 + mt * 16 + g * 4 + i2;
        const float inv = 1.0f / ((sRb[0][rw] + sRb[1][rw]) + (sRb[2][rw] + sRb[3][rw]));
#pragma unroll
        for (int nt = 0; nt < 9; ++nt) {
          const int u = wkv * 18 + nt * 2 + (ln >> 3);
          sPp[rw * 576 + ((u ^ (rw & 7)) << 3) + (ln & 7)] = f2h(acc[mt][nt][i2] * inv);
        }
      }
  }
  __syncthreads();

  // ---------------- PV: per wave [64q x 48d] x 2 passes; V frags direct from global
#pragma unroll 1
  for (int p = 0; p < 2; ++p) {
    f32x4 O[4][3];
#pragma unroll
    for (int mt = 0; mt < 4; ++mt)
#pragma unroll
      for (int nt = 0; nt < 3; ++nt) O[mt][nt] = (f32x4){0.f, 0.f, 0.f, 0.f};

#pragma unroll 1
    for (int kc = 0; kc < 18; ++kc) {
      h8 vf[3];
#pragma unroll
      for (int nt = 0; nt < 3; ++nt)
        vf[nt] = *(const h8*)(VfB + (((size_t)(kc * 48 + w * 6 + p * 3 + nt)) << 9) + lane * 8);
      h8 pa[4];
#pragma unroll
      for (int mt = 0; mt < 4; ++mt) {
        const int row = mt * 16 + ln;
        const int u = kc * 4 + g;
        pa[mt] = *(const h8*)(lds + row * 1152 + ((u ^ (row & 7)) << 4));
      }
#pragma unroll
      for (int nt = 0; nt < 3; ++nt)
#pragma unroll
        for (int mt = 0; mt < 4; ++mt)
          O[mt][nt] = __builtin_amdgcn_mfma_f32_16x16x32_f16(pa[mt], vf[nt], O[mt][nt], 0, 0, 0);
    }

    float* ob = Out + ((size_t)(b * Nn + q0)) * Dd;
#pragma unroll
    for (int mt = 0; mt < 4; ++mt)
#pragma unroll
      for (int nt = 0; nt < 3; ++nt)
#pragma unroll
        for (int i2 = 0; i2 < 4; ++i2)
          ob[(size_t)(mt * 16 + g * 4 + i2) * Dd + w * 96 + p * 48 + nt * 16 + ln] = O[mt][nt][i2];
  }
}

extern "C" void kernel_launch(void* const* d_in, const int* in_sizes, int n_in,
                              void* d_out, int out_size, void* d_ws, size_t ws_size,
                              hipStream_t stream) {
  const float* Q = (const float*)d_in[0];
  const float* K = (const float*)d_in[1];
  float* Out = (float*)d_out;
  unsigned short* Kf = (unsigned short*)d_ws;
  unsigned short* Vf = Kf + KF_ELEMS;
  fusion_prep<<<dim3(Bb * 24), dim3(256), 0, stream>>>(K, Kf, Vf);
  fusion_main<<<dim3(Bb * 16), dim3(512), 0, stream>>>(Q, Kf, Vf, Out);
}

// Round 10
// 129.784 us; speedup vs baseline: 1.6710x; 1.1672x over previous
//
#include <hip/hip_runtime.h>

typedef float f32x4 __attribute__((ext_vector_type(4)));
typedef _Float16 h8 __attribute__((ext_vector_type(8)));
typedef unsigned short us8 __attribute__((ext_vector_type(8)));

#define DEV __device__ __forceinline__
#define SBARRIER() asm volatile("s_barrier" ::: "memory")
#define LGKM0()    asm volatile("s_waitcnt lgkmcnt(0)" ::: "memory")
#define VMCNT3()   asm volatile("s_waitcnt vmcnt(3)" ::: "memory")
#define VMCNT0()   asm volatile("s_waitcnt vmcnt(0)" ::: "memory")
#define SCHED0()   __builtin_amdgcn_sched_barrier(0)

constexpr int Bb = 32, Nn = 1024, Mm = 576, Dd = 768;
constexpr float L2E = 1.44269504088896340736f;

// ws layout (ushort elems), fragment-major for 16x16x32 f16 MFMA:
//   Kf: [b][kvtile 36][dc 24][lane 64][8]   B-frag: K[kvt*16+(l&15)][dc*32+(l>>4)*8+j]
//   Vf: [b][kc 18][dtile 48][lane 64][8]    B-frag: V[kc*32+(l>>4)*8+j][dt*16+(l&15)]
constexpr size_t KF_ELEMS = (size_t)Bb * 36 * 24 * 512;  // 14,155,776

DEV unsigned short f2h(float x) {
  _Float16 h = (_Float16)x;
  return __builtin_bit_cast(unsigned short, h);
}
DEV void gll16(const void* g, void* l) {
  __builtin_amdgcn_global_load_lds(
      (const __attribute__((address_space(1))) void*)g,
      (__attribute__((address_space(3))) void*)l, 16, 0, 0);
}

// ---------------- pre-pass: K -> Kf, Vf (fragment-major f16) — unchanged
__global__ __launch_bounds__(256)
void fusion_prep(const float* __restrict__ K, unsigned short* __restrict__ Kf,
                 unsigned short* __restrict__ Vf)
{
  const int t = threadIdx.x;
  const int b = blockIdx.x / 24, dc = blockIdx.x % 24;
  const int l = t & 63;
  {
    const int lt = t >> 6;
    const int ro = l & 15, go = l >> 4;
#pragma unroll
    for (int it = 0; it < 9; ++it) {
      const int kvt = it * 4 + lt;
      const float* src = K + ((size_t)(b * Mm + kvt * 16 + ro)) * Dd + dc * 32 + go * 8;
      f32x4 v0 = *(const f32x4*)src;
      f32x4 v1 = *(const f32x4*)(src + 4);
      us8 h;
      h[0]=f2h(v0[0]); h[1]=f2h(v0[1]); h[2]=f2h(v0[2]); h[3]=f2h(v0[3]);
      h[4]=f2h(v1[0]); h[5]=f2h(v1[1]); h[6]=f2h(v1[2]); h[7]=f2h(v1[3]);
      *(us8*)&Kf[(((size_t)((b * 36 + kvt) * 24 + dc)) << 9) + l * 8] = h;
    }
  }
  {
    const int kch = t >> 7;
    const int dtl = (t >> 6) & 1;
    const int d = dc * 32 + dtl * 16 + (l & 15);
    const int kvo = (l >> 4) * 8;
#pragma unroll
    for (int it = 0; it < 9; ++it) {
      const int kc = it * 2 + kch;
      const int kv0 = kc * 32 + kvo;
      us8 o;
#pragma unroll
      for (int j = 0; j < 8; ++j)
        o[j] = f2h(K[((size_t)(b * Mm + kv0 + j)) * Dd + d]);
      *(us8*)&Vf[(((size_t)((b * 18 + kc) * 48 + dc * 2 + dtl)) << 9) + l * 8] = o;
    }
  }
}

// ---------------- main: role-split counted-vmcnt QK pipeline (T3/T4/T5), PV vf-dbuf
// LDS (bytes): bufK[3] @ {0,36864,73728}; qbuf[2] @ 110592+{0,16384}
//              sP (128x576 f16, pitch 1152 B, XOR swizzle) aliases 0..147456 after QK
__global__ __launch_bounds__(1024)
void fusion_main(const float* __restrict__ Q, const unsigned short* __restrict__ Kf,
                 const unsigned short* __restrict__ Vf, float* __restrict__ Out)
{
  __shared__ alignas(16) unsigned char lds[147456];
  __shared__ float sRa[4][128];
  __shared__ float sRb[4][128];

  const int tid  = threadIdx.x;
  const int lane = tid & 63;
  const int w    = tid >> 6;      // 0..15
  const int g    = lane >> 4;
  const int ln   = lane & 15;
  const int wq   = w >> 2;        // QK: 0..3, q rows [wq*32,+32)
  const int wkv  = w & 3;         // QK: kv slice [wkv*144,+144)
  const int wq2  = w >> 3;        // PV: 0..1
  const int wd8  = w & 7;         // PV: d slice [wd8*96,+96)

  const bool loader  = (w < 12);  // 3 gll16/chunk, no other vmem in QK loop
  const bool qstager = (w >= 12); // 4 f32x4 Q loads + cvt + ds_write, no gll16

  // XCD swizzle
  const int bid = blockIdx.x;
  const int xcd = bid & 7, ii = bid >> 3;
  const int b  = (xcd << 2) | (ii >> 3);
  const int q0 = (ii & 7) * 128;

  const float* Qb = Q + ((size_t)(b * Nn + q0)) * Dd;
  const unsigned char* KfB = (const unsigned char*)Kf + ((size_t)(b * 36 * 24) << 10);
  const unsigned short* VfB = Vf + ((size_t)(b * 18 * 48) << 9);

  // loader constants: units u0..u0+2 of 36 (1 KB each)
  const int u0 = w * 3;
  // qstager constants: 2 slots, slot s: qt=s>>6, l=s&63
  const int t256 = tid & 255;
  const int s0 = t256, s1 = t256 + 256;
  const int qt0 = s0 >> 6, l0 = s0 & 63;
  const int qt1 = s1 >> 6, l1 = s1 & 63;
  const float* qsrc0 = Qb + (size_t)(qt0 * 16 + (l0 & 15)) * Dd + (l0 >> 4) * 8;
  const float* qsrc1 = Qb + (size_t)(qt1 * 16 + (l1 & 15)) * Dd + (l1 >> 4) * 8;
  unsigned char* qd0 = lds + 110592 + qt0 * 2048 + l0 * 16;
  unsigned char* qd1 = lds + 110592 + qt1 * 2048 + l1 * 16;

  // ---------------- prologue
  {
    f32x4 a0, a1, b0, b1;
    if (qstager) {
      a0 = *(const f32x4*)qsrc0; a1 = *(const f32x4*)(qsrc0 + 4);
      b0 = *(const f32x4*)qsrc1; b1 = *(const f32x4*)(qsrc1 + 4);
    }
    SCHED0();
    if (loader) {
      // CHUNK-MAJOR issue order (vmcnt retires oldest-first): all of K(0),
      // then all of K(1) -> VMCNT3 below guarantees K(0) fully landed.
#pragma unroll
      for (int j = 0; j < 3; ++j)
        gll16(KfB + ((size_t)((u0 + j) * 24) << 10) + (lane << 4), lds + (u0 + j) * 1024);
#pragma unroll
      for (int j = 0; j < 3; ++j)
        gll16(KfB + ((size_t)((u0 + j) * 24 + 1) << 10) + (lane << 4), lds + 36864 + (u0 + j) * 1024);
    }
    if (qstager) {
      us8 h0, v0, h1, v1;
#pragma unroll
      for (int k = 0; k < 4; ++k) {
        float x = a0[k] * L2E; _Float16 hh = (_Float16)x;
        h0[k] = __builtin_bit_cast(unsigned short, hh);
        v0[k] = __builtin_bit_cast(unsigned short, (_Float16)(x - (float)hh));
        float y = a1[k] * L2E; _Float16 jj = (_Float16)y;
        h0[k+4] = __builtin_bit_cast(unsigned short, jj);
        v0[k+4] = __builtin_bit_cast(unsigned short, (_Float16)(y - (float)jj));
        float x2 = b0[k] * L2E; _Float16 hh2 = (_Float16)x2;
        h1[k] = __builtin_bit_cast(unsigned short, hh2);
        v1[k] = __builtin_bit_cast(unsigned short, (_Float16)(x2 - (float)hh2));
        float y2 = b1[k] * L2E; _Float16 jj2 = (_Float16)y2;
        h1[k+4] = __builtin_bit_cast(unsigned short, jj2);
        v1[k+4] = __builtin_bit_cast(unsigned short, (_Float16)(y2 - (float)jj2));
      }
      *(us8*)qd0 = h0; *(us8*)(qd0 + 1024) = v0;
      *(us8*)qd1 = h1; *(us8*)(qd1 + 1024) = v1;
    }
    if (loader) { VMCNT3(); }   // K(0) landed; K(1) in flight
    LGKM0();
    SBARRIER();
    SCHED0();
  }

  // ---------------- QK loop: 1 raw barrier/chunk, counted vmcnt only
  f32x4 acc[2][9];
#pragma unroll
  for (int mt = 0; mt < 2; ++mt)
#pragma unroll
    for (int nt = 0; nt < 9; ++nt) acc[mt][nt] = (f32x4){0.f, 0.f, 0.f, 0.f};

#pragma unroll 1
  for (int c = 0; c < 24; ++c) {
    // Q(c+1) loads first (so qstagers' auto-wait never touches gll16s)
    f32x4 a0, a1, b0, b1;
    if (qstager && c < 23) {
      const size_t off = (size_t)(c + 1) * 32;
      a0 = *(const f32x4*)(qsrc0 + off); a1 = *(const f32x4*)(qsrc0 + off + 4);
      b0 = *(const f32x4*)(qsrc1 + off); b1 = *(const f32x4*)(qsrc1 + off + 4);
    }
    SCHED0();
    // K(c+2) prefetch into bufK[(c+2)%3] (its old data was consumed in chunk c-1)
    if (loader && c < 22) {
      unsigned char* dst = lds + ((c + 2) % 3) * 36864;
#pragma unroll
      for (int j = 0; j < 3; ++j) {
        const int u = u0 + j;
        gll16(KfB + ((size_t)(u * 24 + c + 2) << 10) + (lane << 4), dst + u * 1024);
      }
    }
    // compute on bufK[c%3], qbuf[c&1] (ds_reads + MFMA in one segment: counted lgkm)
    const unsigned char* qb = lds + 110592 + (c & 1) * 16384;
    const unsigned char* kb = lds + (c % 3) * 36864;
    h8 qh[2], ql[2];
#pragma unroll
    for (int mt = 0; mt < 2; ++mt) {
      qh[mt] = *(const h8*)(qb + (wq * 2 + mt) * 2048 + lane * 16);
      ql[mt] = *(const h8*)(qb + (wq * 2 + mt) * 2048 + 1024 + lane * 16);
    }
    __builtin_amdgcn_s_setprio(1);
#pragma unroll
    for (int nt = 0; nt < 9; ++nt) {
      const h8 kf = *(const h8*)(kb + (wkv * 9 + nt) * 1024 + lane * 16);
#pragma unroll
      for (int mt = 0; mt < 2; ++mt) {
        acc[mt][nt] = __builtin_amdgcn_mfma_f32_16x16x32_f16(qh[mt], kf, acc[mt][nt], 0, 0, 0);
        acc[mt][nt] = __builtin_amdgcn_mfma_f32_16x16x32_f16(ql[mt], kf, acc[mt][nt], 0, 0, 0);
      }
    }
    __builtin_amdgcn_s_setprio(0);
    SCHED0();   // keep cvt + ds_writes after the MFMA cluster
    if (qstager && c < 23) {
      us8 h0, v0, h1, v1;
#pragma unroll
      for (int k = 0; k < 4; ++k) {
        float x = a0[k] * L2E; _Float16 hh = (_Float16)x;
        h0[k] = __builtin_bit_cast(unsigned short, hh);
        v0[k] = __builtin_bit_cast(unsigned short, (_Float16)(x - (float)hh));
        float y = a1[k] * L2E; _Float16 jj = (_Float16)y;
        h0[k+4] = __builtin_bit_cast(unsigned short, jj);
        v0[k+4] = __builtin_bit_cast(unsigned short, (_Float16)(y - (float)jj));
        float x2 = b0[k] * L2E; _Float16 hh2 = (_Float16)x2;
        h1[k] = __builtin_bit_cast(unsigned short, hh2);
        v1[k] = __builtin_bit_cast(unsigned short, (_Float16)(x2 - (float)hh2));
        float y2 = b1[k] * L2E; _Float16 jj2 = (_Float16)y2;
        h1[k+4] = __builtin_bit_cast(unsigned short, jj2);
        v1[k+4] = __builtin_bit_cast(unsigned short, (_Float16)(y2 - (float)jj2));
      }
      unsigned char* d0 = qd0 + ((c + 1) & 1) * 16384;
      unsigned char* d1 = qd1 + ((c + 1) & 1) * 16384;
      *(us8*)d0 = h0; *(us8*)(d0 + 1024) = v0;
      *(us8*)d1 = h1; *(us8*)(d1 + 1024) = v1;
    }
    if (loader) {
      if (c <= 21) { VMCNT3(); }   // K(c+1) landed; K(c+2) still in flight
      else         { VMCNT0(); }   // tail drain (loads are a full chunk old)
    }
    LGKM0();
    SBARRIER();
    SCHED0();
  }

  // ---------------- one-shot softmax (exp2 domain; Q pre-scaled by log2 e)
  float pm[2][4];
#pragma unroll
  for (int mt = 0; mt < 2; ++mt)
#pragma unroll
    for (int i2 = 0; i2 < 4; ++i2) {
      float v = acc[mt][0][i2];
#pragma unroll
      for (int nt = 1; nt < 9; ++nt) v = fmaxf(v, acc[mt][nt][i2]);
      pm[mt][i2] = v;
    }
#pragma unroll
  for (int mk = 1; mk < 16; mk <<= 1)
#pragma unroll
    for (int mt = 0; mt < 2; ++mt)
#pragma unroll
      for (int i2 = 0; i2 < 4; ++i2)
        pm[mt][i2] = fmaxf(pm[mt][i2], __shfl_xor(pm[mt][i2], mk, 64));
  if (ln == 0) {
#pragma unroll
    for (int mt = 0; mt < 2; ++mt)
#pragma unroll
      for (int i2 = 0; i2 < 4; ++i2)
        sRa[wkv][wq * 32 + mt * 16 + g * 4 + i2] = pm[mt][i2];
  }
  __syncthreads();

  float mfin[2][4], ps[2][4];
#pragma unroll
  for (int mt = 0; mt < 2; ++mt)
#pragma unroll
    for (int i2 = 0; i2 < 4; ++i2) {
      const int rw = wq * 32 + mt * 16 + g * 4 + i2;
      mfin[mt][i2] = fmaxf(fmaxf(sRa[0][rw], sRa[1][rw]), fmaxf(sRa[2][rw], sRa[3][rw]));
      ps[mt][i2] = 0.f;
    }
#pragma unroll
  for (int mt = 0; mt < 2; ++mt)
#pragma unroll
    for (int nt = 0; nt < 9; ++nt)
#pragma unroll
      for (int i2 = 0; i2 < 4; ++i2) {
        const float p = exp2f(acc[mt][nt][i2] - mfin[mt][i2]);
        acc[mt][nt][i2] = p;
        ps[mt][i2] += p;
      }
#pragma unroll
  for (int mk = 1; mk < 16; mk <<= 1)
#pragma unroll
    for (int mt = 0; mt < 2; ++mt)
#pragma unroll
      for (int i2 = 0; i2 < 4; ++i2)
        ps[mt][i2] += __shfl_xor(ps[mt][i2], mk, 64);
  if (ln == 0) {
#pragma unroll
    for (int mt = 0; mt < 2; ++mt)
#pragma unroll
      for (int i2 = 0; i2 < 4; ++i2)
        sRb[wkv][wq * 32 + mt * 16 + g * 4 + i2] = ps[mt][i2];
  }
  __syncthreads();

  // normalize P -> swizzled sP (aliases dead bufK/qbuf)
  {
    unsigned short* sPp = (unsigned short*)lds;
#pragma unroll
    for (int mt = 0; mt < 2; ++mt)
#pragma unroll
      for (int i2 = 0; i2 < 4; ++i2) {
        const int rw = wq * 32 + mt * 16 + g * 4 + i2;
        const float inv = 1.0f / ((sRb[0][rw] + sRb[1][rw]) + (sRb[2][rw] + sRb[3][rw]));
#pragma unroll
        for (int nt = 0; nt < 9; ++nt) {
          const int u = wkv * 18 + nt * 2 + (ln >> 3);
          sPp[rw * 576 + ((u ^ (rw & 7)) << 3) + (ln & 7)] = f2h(acc[mt][nt][i2] * inv);
        }
      }
  }
  __syncthreads();

  // ---------------- PV: [64q x 96d]/wave x 2 passes; vf double-buffered (2x unroll)
#pragma unroll 1
  for (int p = 0; p < 2; ++p) {
    f32x4 O[4][3];
#pragma unroll
    for (int mt = 0; mt < 4; ++mt)
#pragma unroll
      for (int nt = 0; nt < 3; ++nt) O[mt][nt] = (f32x4){0.f, 0.f, 0.f, 0.f};

    // dtile base for this wave/pass: dt = wd8*6 + p*3 + nt   (R8 bug: had *12/*6)
    const unsigned short* vbase = VfB + ((size_t)(wd8 * 6 + p * 3) << 9) + lane * 8;
    h8 vfA[3], vfB2[3];
#pragma unroll
    for (int nt = 0; nt < 3; ++nt)
      vfA[nt] = *(const h8*)(vbase + ((size_t)nt << 9));

#pragma unroll 1
    for (int kc = 0; kc < 18; kc += 2) {
      // prefetch vf(kc+1)
#pragma unroll
      for (int nt = 0; nt < 3; ++nt)
        vfB2[nt] = *(const h8*)(vbase + ((size_t)((kc + 1) * 48 + nt) << 9));
      {
        h8 pa[4];
#pragma unroll
        for (int mt = 0; mt < 4; ++mt) {
          const int row = wq2 * 64 + mt * 16 + ln;
          const int u = kc * 4 + g;
          pa[mt] = *(const h8*)(lds + row * 1152 + ((u ^ (row & 7)) << 4));
        }
#pragma unroll
        for (int nt = 0; nt < 3; ++nt)
#pragma unroll
          for (int mt = 0; mt < 4; ++mt)
            O[mt][nt] = __builtin_amdgcn_mfma_f32_16x16x32_f16(pa[mt], vfA[nt], O[mt][nt], 0, 0, 0);
      }
      // prefetch vf(kc+2)
      if (kc < 16) {
#pragma unroll
        for (int nt = 0; nt < 3; ++nt)
          vfA[nt] = *(const h8*)(vbase + ((size_t)((kc + 2) * 48 + nt) << 9));
      }
      {
        h8 pa[4];
#pragma unroll
        for (int mt = 0; mt < 4; ++mt) {
          const int row = wq2 * 64 + mt * 16 + ln;
          const int u = (kc + 1) * 4 + g;
          pa[mt] = *(const h8*)(lds + row * 1152 + ((u ^ (row & 7)) << 4));
        }
#pragma unroll
        for (int nt = 0; nt < 3; ++nt)
#pragma unroll
          for (int mt = 0; mt < 4; ++mt)
            O[mt][nt] = __builtin_amdgcn_mfma_f32_16x16x32_f16(pa[mt], vfB2[nt], O[mt][nt], 0, 0, 0);
      }
    }

    float* ob = Out + ((size_t)(b * Nn + q0 + wq2 * 64)) * Dd;
#pragma unroll
    for (int mt = 0; mt < 4; ++mt)
#pragma unroll
      for (int nt = 0; nt < 3; ++nt)
#pragma unroll
        for (int i2 = 0; i2 < 4; ++i2)
          ob[(size_t)(mt * 16 + g * 4 + i2) * Dd + wd8 * 96 + p * 48 + nt * 16 + ln] = O[mt][nt][i2];
  }
}

extern "C" void kernel_launch(void* const* d_in, const int* in_sizes, int n_in,
                              void* d_out, int out_size, void* d_ws, size_t ws_size,
                              hipStream_t stream) {
  const float* Q = (const float*)d_in[0];
  const float* K = (const float*)d_in[1];
  float* Out = (float*)d_out;
  unsigned short* Kf = (unsigned short*)d_ws;
  unsigned short* Vf = Kf + KF_ELEMS;
  fusion_prep<<<dim3(Bb * 24), dim3(256), 0, stream>>>(K, Kf, Vf);
  fusion_main<<<dim3(Bb * 8), dim3(1024), 0, stream>>>(Q, Kf, Vf, Out);
}